// Round 1
// 269.315 us; speedup vs baseline: 1.0695x; 1.0695x over previous
//
#include <hip/hip_runtime.h>

// PerfusionTHGNN on MI355X. Input dtype AUTO-DETECTED (adjacency words).
// 6 dispatches, 0 memsets:
//  k_detect (flag slots)
//  k_imp    (weights->canonical; W1s transposed+padded; zero meanacc)
//  k_gruf   (FAT kernel: blocks 0..255 = GRU reg-gates + lin1->C1 bf16 + f12
//            epilogue; blocks 256..1279 = adjacency->CSR compaction streaming
//            under the GRU's idle HBM pipe. Adjacency read no longer
//            serializes behind the GRU at the ~1.45 TB/s input floor.)
//  k_gat3   (slim: CSR from workspace -> GAT aggregate + lin2)
//  k_sem    (semantic attention, b128 LDS dots, 16 nodes/block, fused mean)
//  k_pred   (pairnorm + MLP [full-wave] + sigmoid)

#define NN 4096

typedef unsigned short u16;
typedef unsigned int   u32;
typedef unsigned long long u64;
typedef __attribute__((ext_vector_type(8))) short  short8;
typedef __attribute__((ext_vector_type(4))) float  float4v;

__device__ inline float bf2f(u16 u){ return __uint_as_float(((u32)u)<<16); }
__device__ inline u16 f2bf(float f){
  u32 x = __float_as_uint(f);
  return (u16)((x + 0x7fffu + ((x>>16)&1u))>>16);   // RNE
}
__device__ inline float ldm(const void* p, int i, int bf){
  return bf ? bf2f(((const u16*)p)[i]) : ((const float*)p)[i];
}
__device__ inline u16 ldm16(const void* p, int i, int bf){
  return bf ? ((const u16*)p)[i] : f2bf(((const float*)p)[i]);
}
__device__ inline float fexp(float x){
  x = fminf(fmaxf(x,-80.f),80.f);
  return __builtin_amdgcn_exp2f(x*1.4426950408889634f);
}
__device__ inline float sigm_fast(float x){          // no clamp: exp2(+-inf) benign here
  return __builtin_amdgcn_rcpf(1.f + __builtin_amdgcn_exp2f(-x*1.4426950408889634f));
}
__device__ inline float tanhf_(float x){
  float c = fminf(fmaxf(x,-15.f),15.f);
  float e = __builtin_amdgcn_exp2f(c*2.8853900817779268f);
  return (e-1.f)*__builtin_amdgcn_rcpf(e+1.f);
}
__device__ inline float4v mfma16(short8 a, short8 b, float4v c){
  return __builtin_amdgcn_mfma_f32_16x16x32_bf16(a,b,c,0,0,0);
}
__device__ inline int rdbf(const int* __restrict__ mflag){
  int b=0;
  #pragma unroll
  for (int k=0;k<16;k++) b|=mflag[k];
  return b;
}

// ---------------------------------------------------------------- k_detect
__global__ __launch_bounds__(256) void k_detect(const u32* __restrict__ adj,
                                                int* __restrict__ mflag)
{
  __shared__ u32 w4[4];
  const int lane=threadIdx.x&63, wv=threadIdx.x>>6;
  int i = (blockIdx.x*256 + threadIdx.x)*4;
  uint4 v = *(const uint4*)(adj + i);
  u32 acc = (v.x | v.y | v.z | v.w) & 0xFFFFu;
  unsigned long long b = __ballot(acc != 0);
  if (lane==0) w4[wv] = (b!=0);
  __syncthreads();
  if (threadIdx.x==0) mflag[blockIdx.x] = (w4[0]|w4[1]|w4[2]|w4[3]) ? 1 : 0;
}

// ---------------------------------------------------------------- k_imp
// WT1 rows: [0,128)=pos_W [128,256)=pos_pW [256,384)=neg_W [384,512)=neg_pW
// [512,640)=self_W.  WT2: [0,128)=mpos_W [128,256)=mneg_W.
// cw1t[c*132+k]=semW1[k][c]; cpw1t[c*132+k]=predW1[k][c].
__global__ __launch_bounds__(256) void k_imp(
  const int* __restrict__ mflag,
  const void* gWih, const void* gWhh, const void* gbih, const void* gbhh,
  const void* posW, const void* posu, const void* posv, const void* posb,
  const void* pospW, const void* pospb,
  const void* negW, const void* negu, const void* negv, const void* negb,
  const void* negpW, const void* negpb,
  const void* selfW, const void* selfb, const void* mposW, const void* mposb,
  const void* mnegW, const void* mnegb,
  const void* semW1, const void* semb1, const void* semW2,
  const void* predW1, const void* predb1, const void* predW2, const void* predb2,
  u16* __restrict__ Wihb, u16* __restrict__ Whhb,
  u16* __restrict__ WT1,  u16* __restrict__ WT2,
  float* __restrict__ cbrz, float* __restrict__ cbin, float* __restrict__ cbhn,
  float* __restrict__ cuv,  float* __restrict__ cgb,  float* __restrict__ csb,
  float* __restrict__ cw1t, float* __restrict__ cb1,  float* __restrict__ cw2,
  float* __restrict__ cpw1t, float* __restrict__ cpb1, float* __restrict__ cpw2,
  float* __restrict__ cpb2, float* __restrict__ meanacc)
{
  const int bf = rdbf(mflag);
  int i = blockIdx.x*256 + threadIdx.x;
  if (i < 6144){ Wihb[i]=ldm16(gWih,i,bf); return; }  i-=6144;
  if (i < 49152){ Whhb[i]=ldm16(gWhh,i,bf); return; } i-=49152;
  if (i < 81920){
    int m=i>>7,k=i&127,sel=m>>7,ml=m&127;
    const void* s = sel==0?posW: sel==1?pospW: sel==2?negW: sel==3?negpW: selfW;
    WT1[i]=ldm16(s,k*128+ml,bf); return;
  } i-=81920;
  if (i < 32768){
    int m=i>>7,k=i&127;
    const void* s = (m<128)? mposW : mnegW;
    WT2[i]=ldm16(s,k*128+(m&127),bf); return;
  } i-=32768;
  if (i < 256){ cbrz[i]=ldm(gbih,i,bf)+ldm(gbhh,i,bf); return; } i-=256;
  if (i < 128){ cbin[i]=ldm(gbih,256+i,bf); return; } i-=128;
  if (i < 128){ cbhn[i]=ldm(gbhh,256+i,bf); return; } i-=128;
  if (i < 512){
    int s=i>>8, rem=i&255, wh=rem>>7, hd=rem&127;
    const void* p = s? (wh? negv:negu) : (wh? posv:posu);
    cuv[i]=ldm(p,hd,bf); return;
  } i-=512;
  if (i < 256){
    int s=i>>7, d=i&127;
    cgb[i]=ldm(s?negb:posb,d,bf)+ldm(s?negpb:pospb,d,bf); return;
  } i-=256;
  if (i < 384){
    int t=i>>7, d=i&127;
    const void* p = t==0? selfb : t==1? mposb : mnegb;
    csb[i]=ldm(p,d,bf); return;
  } i-=384;
  if (i < 8448){
    int c=i/132, k=i-c*132;
    cw1t[i] = (k<128)? ldm(semW1,k*64+c,bf) : 0.f; return;
  } i-=8448;
  if (i < 64){ cb1[i]=ldm(semb1,i,bf); return; } i-=64;
  if (i < 64){ cw2[i]=ldm(semW2,i,bf); return; } i-=64;
  if (i < 4224){
    int c=i/132, k=i-c*132;
    cpw1t[i] = (k<128)? ldm(predW1,k*32+c,bf) : 0.f; return;
  } i-=4224;
  if (i < 32){ cpb1[i]=ldm(predb1,i,bf); return; } i-=32;
  if (i < 32){ cpw2[i]=ldm(predW2,i,bf); return; } i-=32;
  if (i < 1){ cpb2[i]=ldm(predb2,i,bf); return; } i-=1;
  if (i < 128){ meanacc[i]=0.f; return; }
}

// ---------------------------------------------------------------- k_gruf (fat)
// Blocks [0,256): GRU (16 nodes, 8 waves, register gates) -> lin1 (C1b bf16)
//   -> f12.  Feature staging vectorized: uint4 (8 bf16) per lane.
// Blocks [256,1280): adjacency->CSR. One wave per (sign,row): stream the 8KB
//   row, mask->prefix-scan->compact nonzero columns (first 128, same order as
//   the old in-kernel compaction -> bit-identical results) into csri/csrc.
//   These blocks dispatch AFTER the GRU blocks so the GRU critical path gets
//   one block per CU immediately; the CSR stream fills the idle HBM pipe.
__global__ __launch_bounds__(512) void k_gruf(
  const int* __restrict__ mflag, const void* feat,
  const u16* __restrict__ Wihb, const u16* __restrict__ Whhb,
  const float* __restrict__ cbrz, const float* __restrict__ cbin,
  const float* __restrict__ cbhn,
  const u16* __restrict__ WT1, const float* __restrict__ cuv,
  const void* posadj, const void* negadj,
  u16* __restrict__ csri, int* __restrict__ csrc,
  u16* __restrict__ C1b, float* __restrict__ f12)
{
  __shared__ __attribute__((aligned(16))) u16 sh_x[16*392];
  __shared__ __attribute__((aligned(16))) u16 hbuf[2][16*136];
  const int bf = rdbf(mflag);
  const int tid=threadIdx.x, lane=tid&63, wv=tid>>6;

  if (blockIdx.x >= NN/16){
    // ------------------------------------------------ CSR compaction path
    const int c = blockIdx.x - NN/16;          // 0..1023
    const int s = c >> 9;                      // 512 blocks per sign
    const int i = (c & 511)*8 + wv;            // row 0..4095
    const void* adj = s? negadj : posadj;
    u64 mask=0;
    if (bf){
      const u16* rp = (const u16*)adj + (size_t)i*4096;
      #pragma unroll
      for (int it=0; it<8; it++){
        const uint4 vv = *(const uint4*)(rp + it*512 + lane*8);
        u32 w[4]={vv.x,vv.y,vv.z,vv.w};
        #pragma unroll
        for (int q=0;q<4;q++){
          if (w[q]&0xffffu) mask |= 1ull<<(it*8+2*q);
          if (w[q]>>16)     mask |= 1ull<<(it*8+2*q+1);
        }
      }
    } else {
      const float* rp = (const float*)adj + (size_t)i*4096;
      #pragma unroll
      for (int it=0; it<16; it++){
        const uint4 vv = *(const uint4*)(rp + it*256 + lane*4);
        if (vv.x) mask |= 1ull<<(it*4+0);
        if (vv.y) mask |= 1ull<<(it*4+1);
        if (vv.z) mask |= 1ull<<(it*4+2);
        if (vv.w) mask |= 1ull<<(it*4+3);
      }
    }
    int cnt=__popcll(mask);
    int pre=cnt;
    #pragma unroll
    for (int off=1; off<64; off<<=1){
      int o=__shfl_up(pre,off);
      if (lane>=off) pre+=o;
    }
    const int base_p = pre-cnt;
    const int total  = __shfl(pre,63);
    u16* op = csri + ((size_t)s*4096 + i)*128;
    if (base_p < 128){
      u64 mm=mask; int p=base_p;
      while (mm && p<128){
        int b=__ffsll(mm)-1; mm&=mm-1;
        int e = bf ? ((b>>3)*512 + lane*8 + (b&7))
                   : ((b>>2)*256 + lane*4 + (b&3));
        op[p++]=(u16)e;
      }
    }
    if (lane==63) csrc[(size_t)s*4096 + i] = total>128 ? 128 : total;
    return;
  }

  // -------------------------------------------------- GRU path (unchanged)
  const int quad=lane>>4, c15=lane&15;
  const int n0=blockIdx.x*16;

  if (bf){
    const u16* f16p=(const u16*)feat;
    for (int i=tid;i<768;i+=512){                  // 768 uint4 chunks
      int n=i/48, c=(i-n*48)*8;
      *(uint4*)(sh_x + n*392 + c) =
        *(const uint4*)(f16p + (size_t)(n0+n)*384 + c);
    }
  } else {
    const float* f32p=(const float*)feat;
    for (int i=tid;i<1536;i+=512){                 // 1536 float4 chunks
      int n=i/96, c=(i-n*96)*4;
      float4 v = *(const float4*)(f32p + (size_t)(n0+n)*384 + c);
      uint2 pk;
      pk.x = (u32)f2bf(v.x) | ((u32)f2bf(v.y)<<16);
      pk.y = (u32)f2bf(v.z) | ((u32)f2bf(v.w)<<16);
      *(uint2*)(sh_x + n*392 + c) = pk;
    }
  }
  for (int i=tid;i<16*136;i+=512) hbuf[0][i]=0;

  const short8 z8={0,0,0,0,0,0,0,0};
  const float4v z4={0.f,0.f,0.f,0.f};
  short8 bh[3][4], bx3[3];
  #pragma unroll
  for (int g=0;g<3;g++){
    int rowb=(g*8+wv)*16+c15;
    #pragma unroll
    for (int ks=0;ks<4;ks++) bh[g][ks]=*(const short8*)(Whhb+(size_t)rowb*128+ks*32+quad*8);
    bx3[g] = (quad<2)? *(const short8*)(Wihb+(size_t)rowb*16+quad*8) : z8;
  }
  const int j0=wv*16+c15;
  const float brz_r=cbrz[j0], brz_z=cbrz[128+j0];
  const float bin0=cbin[j0],  bhn0=cbhn[j0];
  float hr[4]={0.f,0.f,0.f,0.f};
  __syncthreads();

  for (int t=0;t<24;t++){
    const u16* hb  = hbuf[t&1];
    u16*       hbn = hbuf[(t+1)&1];
    short8 ah[4];
    #pragma unroll
    for (int ks=0;ks<4;ks++) ah[ks]=*(const short8*)(hb + c15*136 + ks*32 + quad*8);
    short8 ax = (quad<2)? *(const short8*)(sh_x + c15*392 + t*16 + quad*8) : z8;
    float4v racc = mfma16(ax,bx3[0],z4);
    float4v zacc = mfma16(ax,bx3[1],z4);
    float4v ni   = mfma16(ax,bx3[2],z4);
    float4v nh   = z4;
    #pragma unroll
    for (int ks=0;ks<4;ks++){
      racc = mfma16(ah[ks],bh[0][ks],racc);
      zacc = mfma16(ah[ks],bh[1][ks],zacc);
      nh   = mfma16(ah[ks],bh[2][ks],nh);
    }
    #pragma unroll
    for (int rr=0;rr<4;rr++){
      const int node = quad*4+rr;
      float r_ = sigm_fast(racc[rr]+brz_r);
      float z_ = sigm_fast(zacc[rr]+brz_z);
      float n_ = tanhf_(ni[rr]+bin0 + r_*(nh[rr]+bhn0));
      float hv = (1.f-z_)*n_ + z_*hr[rr];
      hr[rr]=hv; hbn[node*136+j0]=f2bf(hv);
    }
    __syncthreads();
  }
  short8 a[4];
  #pragma unroll
  for (int ks=0;ks<4;ks++) a[ks]=*(const short8*)(hbuf[0]+c15*136+ks*32+quad*8);
  #pragma unroll
  for (int q=0;q<5;q++){
    int tile=wv*5+q;
    float4v acc={0.f,0.f,0.f,0.f};
    #pragma unroll
    for (int ks=0;ks<4;ks++){
      short8 b=*(const short8*)(WT1+(size_t)(tile*16+c15)*128+ks*32+quad*8);
      acc=mfma16(a[ks],b,acc);
    }
    #pragma unroll
    for (int r=0;r<4;r++)
      C1b[(size_t)(n0+quad*4+r)*640 + tile*16 + c15]=f2bf(acc[r]);
  }
  __syncthreads();
  {
    int q=tid;
    int nl=q&15, h=(q>>4)&3, wsel=(q>>6)&1, s=(q>>7)&1;
    const float* uvp = cuv + s*256 + wsel*128 + h*32;
    const u16*   SL  = C1b + (size_t)(n0+nl)*640 + s*256 + h*32;
    float t=0.f;
    #pragma unroll
    for (int d=0;d<32;d++) t += bf2f(SL[d])*uvp[d];
    f12[s*32768 + wsel*16384 + h*4096 + (n0+nl)] = t;
  }
}

// ---------------------------------------------------------------- k_gat3
// Slim: adjacency compaction moved into k_gruf. Load the CSR row (one dword
// per lane), then edge-weight + aggregate + lin2 exactly as before.
__global__ __launch_bounds__(1024) void k_gat3(
  const u16* __restrict__ csri, const int* __restrict__ csrc,
  const u16* __restrict__ C1b, const float* __restrict__ f12,
  const float* __restrict__ cgb, const u16* __restrict__ WT2,
  float* __restrict__ E)
{
  __shared__ u16   nbuf[16][128];
  __shared__ float wbuf[16][4][128];
  __shared__ __attribute__((aligned(16))) u16 sA[16*136];
  const int s=blockIdx.y;
  const int wv=threadIdx.x>>6, lane=threadIdx.x&63;
  const int n0=blockIdx.x*16;
  const int i=n0+wv;

  ((u32*)nbuf[wv])[lane] = ((const u32*)(csri + ((size_t)s*4096 + i)*128))[lane];
  const int dg = csrc[(size_t)s*4096 + i];

  const float* f1 = f12 + s*32768;
  const float* f2 = f12 + s*32768 + 16384;
  const int d0=lane, d1=lane+64, h0=lane>>5, h1=2+(lane>>5);
  float f2v[4];
  #pragma unroll
  for (int h=0;h<4;h++) f2v[h]=f2[h*4096+i];
  for (int e=lane; e<dg; e+=64){
    int j = nbuf[wv][e];
    #pragma unroll
    for (int h=0;h<4;h++){
      float w = f1[h*4096+j] + f2v[h];
      wbuf[wv][h][e] = w>0.f ? w : 0.2f*w;
    }
  }

  float acc0=0.f,acc1=0.f,rs0=0.f,rs1=0.f;
  #pragma unroll 4
  for (int e=0;e<dg;e++){
    float w0 = wbuf[wv][h0][e];
    float w1 = wbuf[wv][h1][e];
    int j = nbuf[wv][e];
    const u16* SL = C1b + (size_t)j*640 + s*256;
    acc0 += w0*bf2f(SL[d0]); rs0 += w0;
    acc1 += w1*bf2f(SL[d1]); rs1 += w1;
  }
  if (rs0==0.f) rs0=1.f;
  if (rs1==0.f) rs1=1.f;
  const u16* P = C1b + (size_t)i*640 + s*256 + 128;
  sA[wv*136+d0]=f2bf(acc0/rs0 + cgb[s*128+d0] + bf2f(P[d0]));
  sA[wv*136+d1]=f2bf(acc1/rs1 + cgb[s*128+d1] + bf2f(P[d1]));
  __syncthreads();
  if (wv<8){
    const int quad=lane>>4, c15=lane&15;
    short8 a[4];
    #pragma unroll
    for (int ks=0;ks<4;ks++) a[ks]=*(const short8*)(sA+c15*136+ks*32+quad*8);
    const int tile=wv;
    float4v acc={0.f,0.f,0.f,0.f};
    #pragma unroll
    for (int ks=0;ks<4;ks++){
      short8 b=*(const short8*)(WT2+(size_t)(s*128+tile*16+c15)*128+ks*32+quad*8);
      acc=mfma16(a[ks],b,acc);
    }
    #pragma unroll
    for (int r=0;r<4;r++) E[(size_t)(n0+quad*4+r)*256 + s*128 + tile*16 + c15]=acc[r];
  }
}

// ---------------------------------------------------------------- k_sem
// 16 nodes/block; W1 transposed+padded in LDS (stride 132, b128 reads).
// Mean partials in registers -> 128 atomicAdds.
__global__ __launch_bounds__(256) void k_sem(
  const u16* __restrict__ C1b, const float* __restrict__ E,
  const float* __restrict__ csb, const float* __restrict__ cw1t,
  const float* __restrict__ cb1, const float* __restrict__ cw2,
  float* __restrict__ fused, float* __restrict__ meanacc)
{
  __shared__ float sW1t[64*132];
  __shared__ float sW2[64];
  __shared__ float sb1[64];
  __shared__ float sE[4][3][128];
  __shared__ float redm[4][128];
  const int tid=threadIdx.x, wv=tid>>6, lane=tid&63;
  for (int i=tid;i<8448;i+=256) sW1t[i]=cw1t[i];
  if (tid<64){ sW2[tid]=cw2[tid]; sb1[tid]=cb1[tid]; }
  __syncthreads();
  const float* wcol = sW1t + lane*132;
  float macc0=0.f, macc1=0.f;
  for (int u=0;u<4;u++){
    const int n = blockIdx.x*16 + wv*4 + u;
    for (int d=lane; d<128; d+=64){
      sE[wv][0][d] = bf2f(C1b[(size_t)n*640+512+d]) + csb[d];
      sE[wv][1][d] = E[(size_t)n*256 + d]    + csb[128+d];
      sE[wv][2][d] = E[(size_t)n*256+128+d]  + csb[256+d];
    }
    float sc[3];
    #pragma unroll
    for (int s=0;s<3;s++){
      float t = sb1[lane];
      #pragma unroll
      for (int k=0;k<128;k+=4){
        float4 e4 = *(const float4*)&sE[wv][s][k];
        float4 w4 = *(const float4*)&wcol[k];
        t += e4.x*w4.x + e4.y*w4.y + e4.z*w4.z + e4.w*w4.w;
      }
      t = tanhf_(t);
      float p = t*sW2[lane];
      #pragma unroll
      for (int off=32; off; off>>=1) p += __shfl_xor(p, off);
      sc[s]=p;
    }
    float mx = fmaxf(sc[0], fmaxf(sc[1],sc[2]));
    float e0=fexp(sc[0]-mx), e1=fexp(sc[1]-mx), e2=fexp(sc[2]-mx);
    float inv = 1.f/(e0+e1+e2);
    float b0=e0*inv, b1=e1*inv, b2=e2*inv;
    float f0 = b0*sE[wv][0][lane]    + b1*sE[wv][1][lane]    + b2*sE[wv][2][lane];
    float f1 = b0*sE[wv][0][lane+64] + b1*sE[wv][1][lane+64] + b2*sE[wv][2][lane+64];
    fused[(size_t)n*128+lane]    = f0;
    fused[(size_t)n*128+64+lane] = f1;
    macc0 += f0; macc1 += f1;
  }
  redm[wv][lane]=macc0; redm[wv][lane+64]=macc1;
  __syncthreads();
  if (tid<128)
    atomicAdd(&meanacc[tid], redm[0][tid]+redm[1][tid]+redm[2][tid]+redm[3][tid]);
}

// ---------------------------------------------------------------- k_pred
__global__ __launch_bounds__(256) void k_pred(
  const float* __restrict__ fused, const float* __restrict__ meanacc,
  const float* __restrict__ cpw1t, const float* __restrict__ cpb1,
  const float* __restrict__ cpw2, const float* __restrict__ cpb2,
  float* __restrict__ out)
{
  __shared__ float sy[4][128];
  __shared__ float sW1t[32*132];
  __shared__ float sW2[32];
  const int tid=threadIdx.x, wv=tid>>6, lane=tid&63;
  for (int i=tid;i<4224;i+=256) sW1t[i]=cpw1t[i];
  if (tid<32) sW2[tid]=cpw2[tid];
  const int n = blockIdx.x*4 + wv;
  const float inv_n = 1.f/4096.f;
  float x0 = fused[(size_t)n*128+lane]    - meanacc[lane]*inv_n;
  float x1 = fused[(size_t)n*128+64+lane] - meanacc[64+lane]*inv_n;
  float ss = x0*x0 + x1*x1;
  #pragma unroll
  for (int o=32;o;o>>=1) ss += __shfl_xor(ss,o);
  float ir = 1.f/sqrtf(1e-6f + ss);
  sy[wv][lane]=x0*ir; sy[wv][64+lane]=x1*ir;
  __syncthreads();
  const int c = lane&31, half = lane>>5;
  const float* wcol = sW1t + c*132 + half*64;
  const float* yrow = sy[wv] + half*64;
  float h=0.f;
  #pragma unroll
  for (int k=0;k<64;k+=4){
    float4 y4 = *(const float4*)&yrow[k];
    float4 w4 = *(const float4*)&wcol[k];
    h += y4.x*w4.x + y4.y*w4.y + y4.z*w4.z + y4.w*w4.w;
  }
  h += __shfl_xor(h,32);
  h += cpb1[c];
  h = h>0.f? h : 0.f;
  float p = h*sW2[c];
  #pragma unroll
  for (int o=16;o;o>>=1) p += __shfl_xor(p,o);
  if (!lane){
    float z = p + cpb2[0];
    out[n] = __builtin_amdgcn_rcpf(1.f + fexp(-z));
  }
}

// ================================================================ launch
extern "C" void kernel_launch(void* const* d_in, const int* in_sizes, int n_in,
                              void* d_out, int out_size, void* d_ws, size_t ws_size,
                              hipStream_t stream)
{
  const void* feat  =d_in[0];
  const void* posadj=d_in[1];
  const void* negadj=d_in[2];
  const void* gWih  =d_in[3];
  const void* gWhh  =d_in[4];
  const void* gbih  =d_in[5];
  const void* gbhh  =d_in[6];
  const void* posW  =d_in[7];
  const void* posu  =d_in[8];
  const void* posv  =d_in[9];
  const void* posb  =d_in[10];
  const void* pospW =d_in[11];
  const void* pospb =d_in[12];
  const void* negW  =d_in[13];
  const void* negu  =d_in[14];
  const void* negv  =d_in[15];
  const void* negb  =d_in[16];
  const void* negpW =d_in[17];
  const void* negpb =d_in[18];
  const void* selfW =d_in[19];
  const void* selfb =d_in[20];
  const void* mposW =d_in[21];
  const void* mposb =d_in[22];
  const void* mnegW =d_in[23];
  const void* mnegb =d_in[24];
  const void* semW1 =d_in[25];
  const void* semb1 =d_in[26];
  const void* semW2 =d_in[27];
  const void* predW1=d_in[28];
  const void* predb1=d_in[29];
  const void* predW2=d_in[30];
  const void* predb2=d_in[31];

  char* wsb=(char*)d_ws; size_t off=0;
  auto alloc=[&](size_t bytes)->void*{ void* p=wsb+off; off+=(bytes+255)&~(size_t)255; return p; };
  int*   mflag=(int*)  alloc(256);
  u16*   Wihb =(u16*)  alloc(6144*2);
  u16*   Whhb =(u16*)  alloc(49152*2);
  u16*   WT1  =(u16*)  alloc(81920*2);
  u16*   WT2  =(u16*)  alloc(32768*2);
  float* cbrz =(float*)alloc(256*4);
  float* cbin =(float*)alloc(128*4);
  float* cbhn =(float*)alloc(128*4);
  float* cuv  =(float*)alloc(512*4);
  float* cgb  =(float*)alloc(256*4);
  float* csb  =(float*)alloc(384*4);
  float* cw1t =(float*)alloc(8448*4);
  float* cb1  =(float*)alloc(64*4);
  float* cw2  =(float*)alloc(64*4);
  float* cpw1t=(float*)alloc(4224*4);
  float* cpb1 =(float*)alloc(32*4);
  float* cpw2 =(float*)alloc(32*4);
  float* cpb2 =(float*)alloc(4);
  u16*   C1b  =(u16*)  alloc((size_t)NN*640*2);
  float* f12  =(float*)alloc((size_t)65536*4);
  float* E    =(float*)alloc((size_t)NN*256*4);
  float* fused=(float*)alloc((size_t)NN*128*4);
  float* meanacc=(float*)alloc(128*4);
  u16*   csri =(u16*)  alloc((size_t)2*4096*128*2);
  int*   csrc =(int*)  alloc((size_t)2*4096*4);
  (void)ws_size; (void)in_sizes; (void)n_in; (void)out_size;

  k_detect<<<16,          256,0,stream>>>((const u32*)posadj,mflag);
  k_imp   <<<722,         256,0,stream>>>(mflag,gWih,gWhh,gbih,gbhh,
              posW,posu,posv,posb,pospW,pospb,negW,negu,negv,negb,negpW,negpb,
              selfW,selfb,mposW,mposb,mnegW,mnegb,semW1,semb1,semW2,
              predW1,predb1,predW2,predb2,
              Wihb,Whhb,WT1,WT2,cbrz,cbin,cbhn,cuv,cgb,csb,cw1t,cb1,cw2,
              cpw1t,cpb1,cpw2,cpb2,meanacc);
  k_gruf  <<<NN/16+1024,  512,0,stream>>>(mflag,feat,Wihb,Whhb,cbrz,cbin,cbhn,
                                          WT1,cuv,posadj,negadj,csri,csrc,
                                          C1b,f12);
  k_gat3  <<<dim3(256,2),1024,0,stream>>>(csri,csrc,C1b,f12,cgb,WT2,E);
  k_sem   <<<NN/16,       256,0,stream>>>(C1b,E,csb,cw1t,cb1,cw2,fused,meanacc);
  k_pred  <<<NN/4,        256,0,stream>>>(fused,meanacc,cpw1t,cpb1,cpw2,cpb2,(float*)d_out);
}

// Round 2
// 268.827 us; speedup vs baseline: 1.0714x; 1.0018x over previous
//
#include <hip/hip_runtime.h>

// PerfusionTHGNN on MI355X. Input dtype AUTO-DETECTED (adjacency words).
// 6 dispatches, 0 memsets. Adjacency stream SPLIT across two kernels so each
// kernel's compute hides its share of the ~1.45 TB/s input-floor read:
//  k_detect (flag slots)
//  k_imp    (weights->canonical; W1s transposed+padded; zero meanacc)
//  k_gruf   (FAT: blocks 0..255 = GRU + lin1->C1b + f12; blocks 256..895 =
//            CSR compaction of pos rows 0..4095 and neg rows 0..1023
//            (~43.5 MB, balanced against ~29 us GRU))
//  k_gat3   (neg rows >=1024 self-compact inline (orig phase A, ~25 MB);
//            all other rows load CSR from workspace; then GAT + lin2)
//  k_sem    (semantic attention, b128 LDS dots, 16 nodes/block, fused mean)
//  k_pred   (pairnorm + MLP [full-wave] + sigmoid)

#define NN 4096
#define NEG_CSR 1024   // neg rows [0,NEG_CSR) compacted in k_gruf; rest in k_gat3

typedef unsigned short u16;
typedef unsigned int   u32;
typedef unsigned long long u64;
typedef __attribute__((ext_vector_type(8))) short  short8;
typedef __attribute__((ext_vector_type(4))) float  float4v;

__device__ inline float bf2f(u16 u){ return __uint_as_float(((u32)u)<<16); }
__device__ inline u16 f2bf(float f){
  u32 x = __float_as_uint(f);
  return (u16)((x + 0x7fffu + ((x>>16)&1u))>>16);   // RNE
}
__device__ inline float ldm(const void* p, int i, int bf){
  return bf ? bf2f(((const u16*)p)[i]) : ((const float*)p)[i];
}
__device__ inline u16 ldm16(const void* p, int i, int bf){
  return bf ? ((const u16*)p)[i] : f2bf(((const float*)p)[i]);
}
__device__ inline float fexp(float x){
  x = fminf(fmaxf(x,-80.f),80.f);
  return __builtin_amdgcn_exp2f(x*1.4426950408889634f);
}
__device__ inline float sigm_fast(float x){          // no clamp: exp2(+-inf) benign here
  return __builtin_amdgcn_rcpf(1.f + __builtin_amdgcn_exp2f(-x*1.4426950408889634f));
}
__device__ inline float tanhf_(float x){
  float c = fminf(fmaxf(x,-15.f),15.f);
  float e = __builtin_amdgcn_exp2f(c*2.8853900817779268f);
  return (e-1.f)*__builtin_amdgcn_rcpf(e+1.f);
}
__device__ inline float4v mfma16(short8 a, short8 b, float4v c){
  return __builtin_amdgcn_mfma_f32_16x16x32_bf16(a,b,c,0,0,0);
}
__device__ inline int rdbf(const int* __restrict__ mflag){
  int b=0;
  #pragma unroll
  for (int k=0;k<16;k++) b|=mflag[k];
  return b;
}

// ---------------------------------------------------------------- k_detect
__global__ __launch_bounds__(256) void k_detect(const u32* __restrict__ adj,
                                                int* __restrict__ mflag)
{
  __shared__ u32 w4[4];
  const int lane=threadIdx.x&63, wv=threadIdx.x>>6;
  int i = (blockIdx.x*256 + threadIdx.x)*4;
  uint4 v = *(const uint4*)(adj + i);
  u32 acc = (v.x | v.y | v.z | v.w) & 0xFFFFu;
  unsigned long long b = __ballot(acc != 0);
  if (lane==0) w4[wv] = (b!=0);
  __syncthreads();
  if (threadIdx.x==0) mflag[blockIdx.x] = (w4[0]|w4[1]|w4[2]|w4[3]) ? 1 : 0;
}

// ---------------------------------------------------------------- k_imp
// WT1 rows: [0,128)=pos_W [128,256)=pos_pW [256,384)=neg_W [384,512)=neg_pW
// [512,640)=self_W.  WT2: [0,128)=mpos_W [128,256)=mneg_W.
// cw1t[c*132+k]=semW1[k][c]; cpw1t[c*132+k]=predW1[k][c].
__global__ __launch_bounds__(256) void k_imp(
  const int* __restrict__ mflag,
  const void* gWih, const void* gWhh, const void* gbih, const void* gbhh,
  const void* posW, const void* posu, const void* posv, const void* posb,
  const void* pospW, const void* pospb,
  const void* negW, const void* negu, const void* negv, const void* negb,
  const void* negpW, const void* negpb,
  const void* selfW, const void* selfb, const void* mposW, const void* mposb,
  const void* mnegW, const void* mnegb,
  const void* semW1, const void* semb1, const void* semW2,
  const void* predW1, const void* predb1, const void* predW2, const void* predb2,
  u16* __restrict__ Wihb, u16* __restrict__ Whhb,
  u16* __restrict__ WT1,  u16* __restrict__ WT2,
  float* __restrict__ cbrz, float* __restrict__ cbin, float* __restrict__ cbhn,
  float* __restrict__ cuv,  float* __restrict__ cgb,  float* __restrict__ csb,
  float* __restrict__ cw1t, float* __restrict__ cb1,  float* __restrict__ cw2,
  float* __restrict__ cpw1t, float* __restrict__ cpb1, float* __restrict__ cpw2,
  float* __restrict__ cpb2, float* __restrict__ meanacc)
{
  const int bf = rdbf(mflag);
  int i = blockIdx.x*256 + threadIdx.x;
  if (i < 6144){ Wihb[i]=ldm16(gWih,i,bf); return; }  i-=6144;
  if (i < 49152){ Whhb[i]=ldm16(gWhh,i,bf); return; } i-=49152;
  if (i < 81920){
    int m=i>>7,k=i&127,sel=m>>7,ml=m&127;
    const void* s = sel==0?posW: sel==1?pospW: sel==2?negW: sel==3?negpW: selfW;
    WT1[i]=ldm16(s,k*128+ml,bf); return;
  } i-=81920;
  if (i < 32768){
    int m=i>>7,k=i&127;
    const void* s = (m<128)? mposW : mnegW;
    WT2[i]=ldm16(s,k*128+(m&127),bf); return;
  } i-=32768;
  if (i < 256){ cbrz[i]=ldm(gbih,i,bf)+ldm(gbhh,i,bf); return; } i-=256;
  if (i < 128){ cbin[i]=ldm(gbih,256+i,bf); return; } i-=128;
  if (i < 128){ cbhn[i]=ldm(gbhh,256+i,bf); return; } i-=128;
  if (i < 512){
    int s=i>>8, rem=i&255, wh=rem>>7, hd=rem&127;
    const void* p = s? (wh? negv:negu) : (wh? posv:posu);
    cuv[i]=ldm(p,hd,bf); return;
  } i-=512;
  if (i < 256){
    int s=i>>7, d=i&127;
    cgb[i]=ldm(s?negb:posb,d,bf)+ldm(s?negpb:pospb,d,bf); return;
  } i-=256;
  if (i < 384){
    int t=i>>7, d=i&127;
    const void* p = t==0? selfb : t==1? mposb : mnegb;
    csb[i]=ldm(p,d,bf); return;
  } i-=384;
  if (i < 8448){
    int c=i/132, k=i-c*132;
    cw1t[i] = (k<128)? ldm(semW1,k*64+c,bf) : 0.f; return;
  } i-=8448;
  if (i < 64){ cb1[i]=ldm(semb1,i,bf); return; } i-=64;
  if (i < 64){ cw2[i]=ldm(semW2,i,bf); return; } i-=64;
  if (i < 4224){
    int c=i/132, k=i-c*132;
    cpw1t[i] = (k<128)? ldm(predW1,k*32+c,bf) : 0.f; return;
  } i-=4224;
  if (i < 32){ cpb1[i]=ldm(predb1,i,bf); return; } i-=32;
  if (i < 32){ cpw2[i]=ldm(predW2,i,bf); return; } i-=32;
  if (i < 1){ cpb2[i]=ldm(predb2,i,bf); return; } i-=1;
  if (i < 128){ meanacc[i]=0.f; return; }
}

// ---------------------------------------------------------------- k_gruf (fat)
// Blocks [0,256): GRU (16 nodes, 8 waves, register gates) -> lin1 (C1b bf16)
//   -> f12.  Feature staging vectorized: uint4 (8 bf16) per lane.
// Blocks [256,896): adjacency->CSR, one wave per row-task t = (blk-256)*8+wv:
//   t<4096 -> pos row t; t>=4096 -> neg row t-4096 (only rows < NEG_CSR).
//   ~43.5 MB stream, sized to balance against the ~29 us GRU critical path.
__global__ __launch_bounds__(512) void k_gruf(
  const int* __restrict__ mflag, const void* feat,
  const u16* __restrict__ Wihb, const u16* __restrict__ Whhb,
  const float* __restrict__ cbrz, const float* __restrict__ cbin,
  const float* __restrict__ cbhn,
  const u16* __restrict__ WT1, const float* __restrict__ cuv,
  const void* posadj, const void* negadj,
  u16* __restrict__ csri, int* __restrict__ csrc,
  u16* __restrict__ C1b, float* __restrict__ f12)
{
  __shared__ __attribute__((aligned(16))) u16 sh_x[16*392];
  __shared__ __attribute__((aligned(16))) u16 hbuf[2][16*136];
  const int bf = rdbf(mflag);
  const int tid=threadIdx.x, lane=tid&63, wv=tid>>6;

  if (blockIdx.x >= NN/16){
    // ------------------------------------------------ CSR compaction path
    const int t = (blockIdx.x - NN/16)*8 + wv;   // 0..5119
    const int s = (t >= 4096) ? 1 : 0;
    const int i = s ? (t - 4096) : t;            // pos: 0..4095, neg: 0..NEG_CSR-1
    const void* adj = s? negadj : posadj;
    u64 mask=0;
    if (bf){
      const u16* rp = (const u16*)adj + (size_t)i*4096;
      #pragma unroll
      for (int it=0; it<8; it++){
        const uint4 vv = *(const uint4*)(rp + it*512 + lane*8);
        u32 w[4]={vv.x,vv.y,vv.z,vv.w};
        #pragma unroll
        for (int q=0;q<4;q++){
          if (w[q]&0xffffu) mask |= 1ull<<(it*8+2*q);
          if (w[q]>>16)     mask |= 1ull<<(it*8+2*q+1);
        }
      }
    } else {
      const float* rp = (const float*)adj + (size_t)i*4096;
      #pragma unroll
      for (int it=0; it<16; it++){
        const uint4 vv = *(const uint4*)(rp + it*256 + lane*4);
        if (vv.x) mask |= 1ull<<(it*4+0);
        if (vv.y) mask |= 1ull<<(it*4+1);
        if (vv.z) mask |= 1ull<<(it*4+2);
        if (vv.w) mask |= 1ull<<(it*4+3);
      }
    }
    int cnt=__popcll(mask);
    int pre=cnt;
    #pragma unroll
    for (int off=1; off<64; off<<=1){
      int o=__shfl_up(pre,off);
      if (lane>=off) pre+=o;
    }
    const int base_p = pre-cnt;
    const int total  = __shfl(pre,63);
    u16* op = csri + ((size_t)s*4096 + i)*128;
    if (base_p < 128){
      u64 mm=mask; int p=base_p;
      while (mm && p<128){
        int b=__ffsll(mm)-1; mm&=mm-1;
        int e = bf ? ((b>>3)*512 + lane*8 + (b&7))
                   : ((b>>2)*256 + lane*4 + (b&3));
        op[p++]=(u16)e;
      }
    }
    if (lane==63) csrc[(size_t)s*4096 + i] = total>128 ? 128 : total;
    return;
  }

  // -------------------------------------------------- GRU path (unchanged)
  const int quad=lane>>4, c15=lane&15;
  const int n0=blockIdx.x*16;

  if (bf){
    const u16* f16p=(const u16*)feat;
    for (int i=tid;i<768;i+=512){                  // 768 uint4 chunks
      int n=i/48, c=(i-n*48)*8;
      *(uint4*)(sh_x + n*392 + c) =
        *(const uint4*)(f16p + (size_t)(n0+n)*384 + c);
    }
  } else {
    const float* f32p=(const float*)feat;
    for (int i=tid;i<1536;i+=512){                 // 1536 float4 chunks
      int n=i/96, c=(i-n*96)*4;
      float4 v = *(const float4*)(f32p + (size_t)(n0+n)*384 + c);
      uint2 pk;
      pk.x = (u32)f2bf(v.x) | ((u32)f2bf(v.y)<<16);
      pk.y = (u32)f2bf(v.z) | ((u32)f2bf(v.w)<<16);
      *(uint2*)(sh_x + n*392 + c) = pk;
    }
  }
  for (int i=tid;i<16*136;i+=512) hbuf[0][i]=0;

  const short8 z8={0,0,0,0,0,0,0,0};
  const float4v z4={0.f,0.f,0.f,0.f};
  short8 bh[3][4], bx3[3];
  #pragma unroll
  for (int g=0;g<3;g++){
    int rowb=(g*8+wv)*16+c15;
    #pragma unroll
    for (int ks=0;ks<4;ks++) bh[g][ks]=*(const short8*)(Whhb+(size_t)rowb*128+ks*32+quad*8);
    bx3[g] = (quad<2)? *(const short8*)(Wihb+(size_t)rowb*16+quad*8) : z8;
  }
  const int j0=wv*16+c15;
  const float brz_r=cbrz[j0], brz_z=cbrz[128+j0];
  const float bin0=cbin[j0],  bhn0=cbhn[j0];
  float hr[4]={0.f,0.f,0.f,0.f};
  __syncthreads();

  for (int t=0;t<24;t++){
    const u16* hb  = hbuf[t&1];
    u16*       hbn = hbuf[(t+1)&1];
    short8 ah[4];
    #pragma unroll
    for (int ks=0;ks<4;ks++) ah[ks]=*(const short8*)(hb + c15*136 + ks*32 + quad*8);
    short8 ax = (quad<2)? *(const short8*)(sh_x + c15*392 + t*16 + quad*8) : z8;
    float4v racc = mfma16(ax,bx3[0],z4);
    float4v zacc = mfma16(ax,bx3[1],z4);
    float4v ni   = mfma16(ax,bx3[2],z4);
    float4v nh   = z4;
    #pragma unroll
    for (int ks=0;ks<4;ks++){
      racc = mfma16(ah[ks],bh[0][ks],racc);
      zacc = mfma16(ah[ks],bh[1][ks],zacc);
      nh   = mfma16(ah[ks],bh[2][ks],nh);
    }
    #pragma unroll
    for (int rr=0;rr<4;rr++){
      const int node = quad*4+rr;
      float r_ = sigm_fast(racc[rr]+brz_r);
      float z_ = sigm_fast(zacc[rr]+brz_z);
      float n_ = tanhf_(ni[rr]+bin0 + r_*(nh[rr]+bhn0));
      float hv = (1.f-z_)*n_ + z_*hr[rr];
      hr[rr]=hv; hbn[node*136+j0]=f2bf(hv);
    }
    __syncthreads();
  }
  short8 a[4];
  #pragma unroll
  for (int ks=0;ks<4;ks++) a[ks]=*(const short8*)(hbuf[0]+c15*136+ks*32+quad*8);
  #pragma unroll
  for (int q=0;q<5;q++){
    int tile=wv*5+q;
    float4v acc={0.f,0.f,0.f,0.f};
    #pragma unroll
    for (int ks=0;ks<4;ks++){
      short8 b=*(const short8*)(WT1+(size_t)(tile*16+c15)*128+ks*32+quad*8);
      acc=mfma16(a[ks],b,acc);
    }
    #pragma unroll
    for (int r=0;r<4;r++)
      C1b[(size_t)(n0+quad*4+r)*640 + tile*16 + c15]=f2bf(acc[r]);
  }
  __syncthreads();
  {
    int q=tid;
    int nl=q&15, h=(q>>4)&3, wsel=(q>>6)&1, s=(q>>7)&1;
    const float* uvp = cuv + s*256 + wsel*128 + h*32;
    const u16*   SL  = C1b + (size_t)(n0+nl)*640 + s*256 + h*32;
    float t=0.f;
    #pragma unroll
    for (int d=0;d<32;d++) t += bf2f(SL[d])*uvp[d];
    f12[s*32768 + wsel*16384 + h*4096 + (n0+nl)] = t;
  }
}

// ---------------------------------------------------------------- k_gat3
// neg rows >= NEG_CSR: stream + compact own adjacency rows inline (identical
// code/order as k_gruf's CSR -> bit-identical). Everything else loads the
// precomputed CSR row (one dword/lane). Then edge-weight + aggregate + lin2.
__global__ __launch_bounds__(1024) void k_gat3(
  const int* __restrict__ mflag,
  const void* posadj, const void* negadj,
  const u16* __restrict__ csri, const int* __restrict__ csrc,
  const u16* __restrict__ C1b, const float* __restrict__ f12,
  const float* __restrict__ cgb, const u16* __restrict__ WT2,
  float* __restrict__ E)
{
  __shared__ u16   nbuf[16][128];
  __shared__ float wbuf[16][4][128];
  __shared__ __attribute__((aligned(16))) u16 sA[16*136];
  const int s=blockIdx.y;
  const int wv=threadIdx.x>>6, lane=threadIdx.x&63;
  const int n0=blockIdx.x*16;
  const int i=n0+wv;

  int dg;
  if (s==1 && n0 >= NEG_CSR){
    // ------------------------------------------ inline compaction (phase A)
    const int bf = rdbf(mflag);
    u64 mask=0;
    if (bf){
      const u16* rp = (const u16*)negadj + (size_t)i*4096;
      #pragma unroll
      for (int it=0; it<8; it++){
        const uint4 vv = *(const uint4*)(rp + it*512 + lane*8);
        u32 w[4]={vv.x,vv.y,vv.z,vv.w};
        #pragma unroll
        for (int q=0;q<4;q++){
          if (w[q]&0xffffu) mask |= 1ull<<(it*8+2*q);
          if (w[q]>>16)     mask |= 1ull<<(it*8+2*q+1);
        }
      }
    } else {
      const float* rp = (const float*)negadj + (size_t)i*4096;
      #pragma unroll
      for (int it=0; it<16; it++){
        const uint4 vv = *(const uint4*)(rp + it*256 + lane*4);
        if (vv.x) mask |= 1ull<<(it*4+0);
        if (vv.y) mask |= 1ull<<(it*4+1);
        if (vv.z) mask |= 1ull<<(it*4+2);
        if (vv.w) mask |= 1ull<<(it*4+3);
      }
    }
    int cnt=__popcll(mask);
    int pre=cnt;
    #pragma unroll
    for (int off=1; off<64; off<<=1){
      int o=__shfl_up(pre,off);
      if (lane>=off) pre+=o;
    }
    const int base_p = pre-cnt;
    const int total  = __shfl(pre,63);
    if (base_p < 128){
      u64 mm=mask; int p=base_p;
      while (mm && p<128){
        int b=__ffsll(mm)-1; mm&=mm-1;
        int e = bf ? ((b>>3)*512 + lane*8 + (b&7))
                   : ((b>>2)*256 + lane*4 + (b&3));
        nbuf[wv][p++]=(u16)e;
      }
    }
    dg = total>128 ? 128 : total;
  } else {
    ((u32*)nbuf[wv])[lane] = ((const u32*)(csri + ((size_t)s*4096 + i)*128))[lane];
    dg = csrc[(size_t)s*4096 + i];
  }

  const float* f1 = f12 + s*32768;
  const float* f2 = f12 + s*32768 + 16384;
  const int d0=lane, d1=lane+64, h0=lane>>5, h1=2+(lane>>5);
  float f2v[4];
  #pragma unroll
  for (int h=0;h<4;h++) f2v[h]=f2[h*4096+i];
  for (int e=lane; e<dg; e+=64){
    int j = nbuf[wv][e];
    #pragma unroll
    for (int h=0;h<4;h++){
      float w = f1[h*4096+j] + f2v[h];
      wbuf[wv][h][e] = w>0.f ? w : 0.2f*w;
    }
  }

  float acc0=0.f,acc1=0.f,rs0=0.f,rs1=0.f;
  #pragma unroll 4
  for (int e=0;e<dg;e++){
    float w0 = wbuf[wv][h0][e];
    float w1 = wbuf[wv][h1][e];
    int j = nbuf[wv][e];
    const u16* SL = C1b + (size_t)j*640 + s*256;
    acc0 += w0*bf2f(SL[d0]); rs0 += w0;
    acc1 += w1*bf2f(SL[d1]); rs1 += w1;
  }
  if (rs0==0.f) rs0=1.f;
  if (rs1==0.f) rs1=1.f;
  const u16* P = C1b + (size_t)i*640 + s*256 + 128;
  sA[wv*136+d0]=f2bf(acc0/rs0 + cgb[s*128+d0] + bf2f(P[d0]));
  sA[wv*136+d1]=f2bf(acc1/rs1 + cgb[s*128+d1] + bf2f(P[d1]));
  __syncthreads();
  if (wv<8){
    const int quad=lane>>4, c15=lane&15;
    short8 a[4];
    #pragma unroll
    for (int ks=0;ks<4;ks++) a[ks]=*(const short8*)(sA+c15*136+ks*32+quad*8);
    const int tile=wv;
    float4v acc={0.f,0.f,0.f,0.f};
    #pragma unroll
    for (int ks=0;ks<4;ks++){
      short8 b=*(const short8*)(WT2+(size_t)(s*128+tile*16+c15)*128+ks*32+quad*8);
      acc=mfma16(a[ks],b,acc);
    }
    #pragma unroll
    for (int r=0;r<4;r++) E[(size_t)(n0+quad*4+r)*256 + s*128 + tile*16 + c15]=acc[r];
  }
}

// ---------------------------------------------------------------- k_sem
// 16 nodes/block; W1 transposed+padded in LDS (stride 132, b128 reads).
// Mean partials in registers -> 128 atomicAdds.
__global__ __launch_bounds__(256) void k_sem(
  const u16* __restrict__ C1b, const float* __restrict__ E,
  const float* __restrict__ csb, const float* __restrict__ cw1t,
  const float* __restrict__ cb1, const float* __restrict__ cw2,
  float* __restrict__ fused, float* __restrict__ meanacc)
{
  __shared__ float sW1t[64*132];
  __shared__ float sW2[64];
  __shared__ float sb1[64];
  __shared__ float sE[4][3][128];
  __shared__ float redm[4][128];
  const int tid=threadIdx.x, wv=tid>>6, lane=tid&63;
  for (int i=tid;i<8448;i+=256) sW1t[i]=cw1t[i];
  if (tid<64){ sW2[tid]=cw2[tid]; sb1[tid]=cb1[tid]; }
  __syncthreads();
  const float* wcol = sW1t + lane*132;
  float macc0=0.f, macc1=0.f;
  for (int u=0;u<4;u++){
    const int n = blockIdx.x*16 + wv*4 + u;
    for (int d=lane; d<128; d+=64){
      sE[wv][0][d] = bf2f(C1b[(size_t)n*640+512+d]) + csb[d];
      sE[wv][1][d] = E[(size_t)n*256 + d]    + csb[128+d];
      sE[wv][2][d] = E[(size_t)n*256+128+d]  + csb[256+d];
    }
    float sc[3];
    #pragma unroll
    for (int s=0;s<3;s++){
      float t = sb1[lane];
      #pragma unroll
      for (int k=0;k<128;k+=4){
        float4 e4 = *(const float4*)&sE[wv][s][k];
        float4 w4 = *(const float4*)&wcol[k];
        t += e4.x*w4.x + e4.y*w4.y + e4.z*w4.z + e4.w*w4.w;
      }
      t = tanhf_(t);
      float p = t*sW2[lane];
      #pragma unroll
      for (int off=32; off; off>>=1) p += __shfl_xor(p, off);
      sc[s]=p;
    }
    float mx = fmaxf(sc[0], fmaxf(sc[1],sc[2]));
    float e0=fexp(sc[0]-mx), e1=fexp(sc[1]-mx), e2=fexp(sc[2]-mx);
    float inv = 1.f/(e0+e1+e2);
    float b0=e0*inv, b1=e1*inv, b2=e2*inv;
    float f0 = b0*sE[wv][0][lane]    + b1*sE[wv][1][lane]    + b2*sE[wv][2][lane];
    float f1 = b0*sE[wv][0][lane+64] + b1*sE[wv][1][lane+64] + b2*sE[wv][2][lane+64];
    fused[(size_t)n*128+lane]    = f0;
    fused[(size_t)n*128+64+lane] = f1;
    macc0 += f0; macc1 += f1;
  }
  redm[wv][lane]=macc0; redm[wv][lane+64]=macc1;
  __syncthreads();
  if (tid<128)
    atomicAdd(&meanacc[tid], redm[0][tid]+redm[1][tid]+redm[2][tid]+redm[3][tid]);
}

// ---------------------------------------------------------------- k_pred
__global__ __launch_bounds__(256) void k_pred(
  const float* __restrict__ fused, const float* __restrict__ meanacc,
  const float* __restrict__ cpw1t, const float* __restrict__ cpb1,
  const float* __restrict__ cpw2, const float* __restrict__ cpb2,
  float* __restrict__ out)
{
  __shared__ float sy[4][128];
  __shared__ float sW1t[32*132];
  __shared__ float sW2[32];
  const int tid=threadIdx.x, wv=tid>>6, lane=tid&63;
  for (int i=tid;i<4224;i+=256) sW1t[i]=cpw1t[i];
  if (tid<32) sW2[tid]=cpw2[tid];
  const int n = blockIdx.x*4 + wv;
  const float inv_n = 1.f/4096.f;
  float x0 = fused[(size_t)n*128+lane]    - meanacc[lane]*inv_n;
  float x1 = fused[(size_t)n*128+64+lane] - meanacc[64+lane]*inv_n;
  float ss = x0*x0 + x1*x1;
  #pragma unroll
  for (int o=32;o;o>>=1) ss += __shfl_xor(ss,o);
  float ir = 1.f/sqrtf(1e-6f + ss);
  sy[wv][lane]=x0*ir; sy[wv][64+lane]=x1*ir;
  __syncthreads();
  const int c = lane&31, half = lane>>5;
  const float* wcol = sW1t + c*132 + half*64;
  const float* yrow = sy[wv] + half*64;
  float h=0.f;
  #pragma unroll
  for (int k=0;k<64;k+=4){
    float4 y4 = *(const float4*)&yrow[k];
    float4 w4 = *(const float4*)&wcol[k];
    h += y4.x*w4.x + y4.y*w4.y + y4.z*w4.z + y4.w*w4.w;
  }
  h += __shfl_xor(h,32);
  h += cpb1[c];
  h = h>0.f? h : 0.f;
  float p = h*sW2[c];
  #pragma unroll
  for (int o=16;o;o>>=1) p += __shfl_xor(p,o);
  if (!lane){
    float z = p + cpb2[0];
    out[n] = __builtin_amdgcn_rcpf(1.f + fexp(-z));
  }
}

// ================================================================ launch
extern "C" void kernel_launch(void* const* d_in, const int* in_sizes, int n_in,
                              void* d_out, int out_size, void* d_ws, size_t ws_size,
                              hipStream_t stream)
{
  const void* feat  =d_in[0];
  const void* posadj=d_in[1];
  const void* negadj=d_in[2];
  const void* gWih  =d_in[3];
  const void* gWhh  =d_in[4];
  const void* gbih  =d_in[5];
  const void* gbhh  =d_in[6];
  const void* posW  =d_in[7];
  const void* posu  =d_in[8];
  const void* posv  =d_in[9];
  const void* posb  =d_in[10];
  const void* pospW =d_in[11];
  const void* pospb =d_in[12];
  const void* negW  =d_in[13];
  const void* negu  =d_in[14];
  const void* negv  =d_in[15];
  const void* negb  =d_in[16];
  const void* negpW =d_in[17];
  const void* negpb =d_in[18];
  const void* selfW =d_in[19];
  const void* selfb =d_in[20];
  const void* mposW =d_in[21];
  const void* mposb =d_in[22];
  const void* mnegW =d_in[23];
  const void* mnegb =d_in[24];
  const void* semW1 =d_in[25];
  const void* semb1 =d_in[26];
  const void* semW2 =d_in[27];
  const void* predW1=d_in[28];
  const void* predb1=d_in[29];
  const void* predW2=d_in[30];
  const void* predb2=d_in[31];

  char* wsb=(char*)d_ws; size_t off=0;
  auto alloc=[&](size_t bytes)->void*{ void* p=wsb+off; off+=(bytes+255)&~(size_t)255; return p; };
  int*   mflag=(int*)  alloc(256);
  u16*   Wihb =(u16*)  alloc(6144*2);
  u16*   Whhb =(u16*)  alloc(49152*2);
  u16*   WT1  =(u16*)  alloc(81920*2);
  u16*   WT2  =(u16*)  alloc(32768*2);
  float* cbrz =(float*)alloc(256*4);
  float* cbin =(float*)alloc(128*4);
  float* cbhn =(float*)alloc(128*4);
  float* cuv  =(float*)alloc(512*4);
  float* cgb  =(float*)alloc(256*4);
  float* csb  =(float*)alloc(384*4);
  float* cw1t =(float*)alloc(8448*4);
  float* cb1  =(float*)alloc(64*4);
  float* cw2  =(float*)alloc(64*4);
  float* cpw1t=(float*)alloc(4224*4);
  float* cpb1 =(float*)alloc(32*4);
  float* cpw2 =(float*)alloc(32*4);
  float* cpb2 =(float*)alloc(4);
  u16*   C1b  =(u16*)  alloc((size_t)NN*640*2);
  float* f12  =(float*)alloc((size_t)65536*4);
  float* E    =(float*)alloc((size_t)NN*256*4);
  float* fused=(float*)alloc((size_t)NN*128*4);
  float* meanacc=(float*)alloc(128*4);
  u16*   csri =(u16*)  alloc((size_t)2*4096*128*2);
  int*   csrc =(int*)  alloc((size_t)2*4096*4);
  (void)ws_size; (void)in_sizes; (void)n_in; (void)out_size;

  k_detect<<<16,          256,0,stream>>>((const u32*)posadj,mflag);
  k_imp   <<<722,         256,0,stream>>>(mflag,gWih,gWhh,gbih,gbhh,
              posW,posu,posv,posb,pospW,pospb,negW,negu,negv,negb,negpW,negpb,
              selfW,selfb,mposW,mposb,mnegW,mnegb,semW1,semb1,semW2,
              predW1,predb1,predW2,predb2,
              Wihb,Whhb,WT1,WT2,cbrz,cbin,cbhn,cuv,cgb,csb,cw1t,cb1,cw2,
              cpw1t,cpb1,cpw2,cpb2,meanacc);
  k_gruf  <<<NN/16 + (NN+NEG_CSR)/8, 512,0,stream>>>(mflag,feat,Wihb,Whhb,
                                          cbrz,cbin,cbhn,WT1,cuv,
                                          posadj,negadj,csri,csrc,C1b,f12);
  k_gat3  <<<dim3(256,2),1024,0,stream>>>(mflag,posadj,negadj,csri,csrc,
                                          C1b,f12,cgb,WT2,E);
  k_sem   <<<NN/16,       256,0,stream>>>(C1b,E,csb,cw1t,cb1,cw2,fused,meanacc);
  k_pred  <<<NN/4,        256,0,stream>>>(fused,meanacc,cpw1t,cpb1,cpw2,cpb2,(float*)d_out);
}